// Round 3
// baseline (141.325 us; speedup 1.0000x reference)
//
#include <hip/hip_runtime.h>

// MinEuclideanDistBlock: x(32,8,4096) f32, shapelets(8,128,64) f32 -> out(32,1,128) f32
// out[b,k] = min_w sum_c sqrt( xnorm[b,c,w] + snorm[c,k] - 2*sum_s x[b,c,w+s]*h[c,k,s] )
//
// R5 -> R6 changes (post-mortem: Occ 19% = 3 blocks/CU resident vs grid 4/CU -> tail
// round at 1/3 load; barrier+vmcnt(0) lockstep per c-iter):
//  - Bs LDS eliminated: B fragments read directly from global hbf (128 KB, L2-resident,
//    un-swizzled now). No DMA, no double-buffer, no vmcnt-at-barrier coupling.
//  - Xr stages ALL 8 channels once in the prologue (25.6 KB); xnormC 4 KB; snorm read
//    from global. LDS 47.6 -> 29.7 KB -> 4 blocks/CU = exactly grid/CU (single round).
//  - ONE __syncthreads total; main loop is barrier-free -> 16 waves/CU free-run.
//  - K processed in 2 halves (gh): dist 64 -> 32 VGPRs; #pragma unroll 1 on gh/c loops
//    pins pressure (target <=128 VGPR for 4 waves/SIMD).

typedef short short8 __attribute__((ext_vector_type(8)));
typedef float f32x4 __attribute__((ext_vector_type(4)));

constexpr int Bn = 32, Cn = 8, Ln = 4096, Kn = 128, Sn = 64;
constexpr int Wn = Ln - Sn + 1;          // 4033
constexpr int WT = 128;                  // windows per block
constexpr int NWT = (Wn + WT - 1) / WT;  // 32
constexpr int BDIM = 256;

__device__ __forceinline__ unsigned int f2bf(float f) {
  unsigned int u = __float_as_uint(f);
  u += 0x7FFFu + ((u >> 16) & 1u);       // round-to-nearest-even
  return u >> 16;
}

// ws layout: [0, 128KB): ushort hbf[C][K][S] = bf16(-2*h), PLAIN layout (no swizzle)
//            [128KB, +4KB): float snorm[C][K]
__global__ void prep_kernel(const float* __restrict__ sh,
                            unsigned int* __restrict__ out,
                            unsigned short* __restrict__ hbf,
                            float* __restrict__ snorm) {
  int gid = blockIdx.x * blockDim.x + threadIdx.x;  // 0..4095
  out[gid] = 0x7F7FFFFFu;                           // FLT_MAX bits (Bn*Kn == 4096)
  if (gid < Cn * Kn) {
    const float4* row = (const float4*)(sh + (size_t)gid * Sn);
    uint2* orow = (uint2*)(hbf + (size_t)gid * Sn);
    float a = 0.f;
    #pragma unroll
    for (int i = 0; i < 16; ++i) {
      float4 v = row[i];
      a += v.x * v.x + v.y * v.y + v.z * v.z + v.w * v.w;
      unsigned int p0 = f2bf(-2.f * v.x) | (f2bf(-2.f * v.y) << 16);
      unsigned int p1 = f2bf(-2.f * v.z) | (f2bf(-2.f * v.w) << 16);
      orow[i] = make_uint2(p0, p1);
    }
    snorm[gid] = a;
  }
}

__launch_bounds__(BDIM, 2)
__global__ void med_kernel(const float* __restrict__ x,
                           const unsigned short* __restrict__ hbf,
                           const float* __restrict__ snorm,
                           unsigned int* __restrict__ out) {
  constexpr int XRS = 200;  // Xr row stride (elems); 400B, 16B-aligned rows
  __shared__ __align__(16) unsigned short Xr[Cn][8 * XRS];  // 25.6 KB, all channels
  __shared__ __align__(16) float xnormC[Cn * WT];           // 4 KB

  const int tid  = threadIdx.x;
  const int b    = blockIdx.y;
  const int w0   = blockIdx.x * WT;
  const int lane = tid & 63;
  const int wv   = tid >> 6;     // wave 0..3
  const int quad = lane >> 4;    // 0..3
  const int n16  = lane & 15;
  const int wbase = wv * 32;     // this wave's window offset in tile

  const float* xb = x + (size_t)b * Cn * Ln;

  // ---- prologue: stage ALL channels' shifted bf16 rows (once) ----
  int x_lds[3], x_g[3];
  #pragma unroll
  for (int rep = 0; rep < 3; ++rep) {
    int pid = tid + rep * BDIM;       // 0..767
    int r = pid / 96;
    int p = pid - r * 96;             // pair index 0..95 -> elems 2p,2p+1
    x_lds[rep] = r * XRS + 2 * p;
    x_g[rep] = w0 + r + 2 * p;
  }
  const bool safe = (w0 + 198 <= Ln);  // only the last w-tile needs masking
  #pragma unroll 1
  for (int c = 0; c < Cn; ++c) {
    const float* xc = xb + (size_t)c * Ln;
    #pragma unroll
    for (int rep = 0; rep < 3; ++rep) {
      float f0, f1;
      if (safe) {
        f0 = xc[x_g[rep]];
        f1 = xc[x_g[rep] + 1];
      } else {
        f0 = (x_g[rep] < Ln) ? xc[x_g[rep]] : 0.f;
        f1 = (x_g[rep] + 1 < Ln) ? xc[x_g[rep] + 1] : 0.f;
      }
      *(unsigned int*)(&Xr[c][x_lds[rep]]) = f2bf(f0) | (f2bf(f1) << 16);
    }
  }

  // xnorm: 256 threads = 8c x 32 groups, 4 windows each (rolling update), fp32-exact
  {
    int c  = tid >> 5;
    int m0 = (tid & 31) * 4;
    const float* xc = xb + c * Ln;
    auto xq = [&](int i) -> float {
      float v = (i < Ln) ? xc[i] : 0.f;
      return v * v;
    };
    float a0 = 0.f, a1 = 0.f, a2 = 0.f, a3 = 0.f;  // 4-acc ILP on the 64-sum
    for (int s = 0; s < Sn; s += 4) {
      a0 += xq(w0 + m0 + s);
      a1 += xq(w0 + m0 + s + 1);
      a2 += xq(w0 + m0 + s + 2);
      a3 += xq(w0 + m0 + s + 3);
    }
    float s0 = (a0 + a1) + (a2 + a3);
    float s1 = s0 - xq(w0 + m0 + 0) + xq(w0 + m0 + 64);
    float s2 = s1 - xq(w0 + m0 + 1) + xq(w0 + m0 + 65);
    float s3 = s2 - xq(w0 + m0 + 2) + xq(w0 + m0 + 66);
    xnormC[c * WT + m0 + 0] = s0;
    xnormC[c * WT + m0 + 1] = s1;
    xnormC[c * WT + m0 + 2] = s2;
    xnormC[c * WT + m0 + 3] = s3;
  }
  __syncthreads();   // the ONLY barrier

  const int wql = w0 + wbase + quad * 4;
  // per-lane byte position inside a 64-row B half-slab: k-row n16, 16B chunk quad
  const char* hbase = (const char*)hbf + n16 * 128 + quad * 16;

  #pragma unroll 1
  for (int gh = 0; gh < 2; ++gh) {
    float dist[4][2][4] = {};  // [gl][mt][rg], accumulated over c

    #pragma unroll 1
    for (int c = 0; c < Cn; ++c) {
      // A fragments for this channel: lane m = n16, k = quad*8+j (+ks*32)
      short8 af[2][2];
      #pragma unroll
      for (int mt = 0; mt < 2; ++mt)
        #pragma unroll
        for (int ks = 0; ks < 2; ++ks) {
          int i = wbase + mt * 16 + n16 + ks * 32 + quad * 8;
          af[mt][ks] = *(const short8*)(&Xr[c][(i & 7) * XRS + (i >> 3) * 8]);
        }
      float4 xn[2];
      #pragma unroll
      for (int mt = 0; mt < 2; ++mt)
        xn[mt] = *(const float4*)(&xnormC[c * WT + wbase + mt * 16 + quad * 4]);

      // B half-slab for (c, gh): 8KB in L2/L1, read as dwordx4 fragments
      const char* hc = hbase + (c * Kn + gh * 64) * (Sn * 2);
      const float* snc = snorm + c * Kn + gh * 64 + n16;

      #pragma unroll
      for (int gl = 0; gl < 4; ++gl) {
        short8 b0 = *(const short8*)(hc + gl * 2048);
        short8 b1 = *(const short8*)(hc + gl * 2048 + 64);
        float sn = snc[gl * 16];
        #pragma unroll
        for (int mt = 0; mt < 2; ++mt) {
          f32x4 acc;
          #pragma unroll
          for (int rg = 0; rg < 4; ++rg) acc[rg] = xn[mt][rg] + sn;
          acc = __builtin_amdgcn_mfma_f32_16x16x32_bf16(af[mt][0], b0, acc, 0, 0, 0);
          acc = __builtin_amdgcn_mfma_f32_16x16x32_bf16(af[mt][1], b1, acc, 0, 0, 0);
          // acc == d2 (norms preloaded in C, -2 folded into B)
          #pragma unroll
          for (int rg = 0; rg < 4; ++rg)
            dist[gl][mt][rg] += __builtin_amdgcn_sqrtf(acc[rg]);
        }
      }
    }

    // ---- min over windows for this k-half, then global combine ----
    #pragma unroll
    for (int gl = 0; gl < 4; ++gl) {
      float v = 3.4e38f;
      #pragma unroll
      for (int mt = 0; mt < 2; ++mt)
        #pragma unroll
        for (int rg = 0; rg < 4; ++rg) {
          int wg = wql + mt * 16 + rg;
          float d = (wg < Wn) ? dist[gl][mt][rg] : 3.4e38f;
          v = fminf(v, d);
        }
      v = fminf(v, __shfl_xor(v, 16, 64));
      v = fminf(v, __shfl_xor(v, 32, 64));
      if (lane < 16)
        atomicMin(&out[b * Kn + (gh * 4 + gl) * 16 + n16], __float_as_uint(v));
    }
  }
}

extern "C" void kernel_launch(void* const* d_in, const int* in_sizes, int n_in,
                              void* d_out, int out_size, void* d_ws, size_t ws_size,
                              hipStream_t stream) {
  const float* x  = (const float*)d_in[0];
  const float* sh = (const float*)d_in[1];
  unsigned int* out = (unsigned int*)d_out;
  unsigned short* hbf = (unsigned short*)d_ws;                      // 128 KB
  float* snorm = (float*)((char*)d_ws + (size_t)Cn * Kn * Sn * 2);  // +4 KB
  hipLaunchKernelGGL(prep_kernel, dim3(16), dim3(256), 0, stream, sh, out, hbf, snorm);
  hipLaunchKernelGGL(med_kernel, dim3(NWT, Bn), dim3(BDIM), 0, stream, x, hbf, snorm, out);
}

// Round 4
// 123.801 us; speedup vs baseline: 1.1416x; 1.1416x over previous
//
#include <hip/hip_runtime.h>

// MinEuclideanDistBlock: x(32,8,4096) f32, shapelets(8,128,64) f32 -> out(32,1,128) f32
// out[b,k] = min_w sum_c sqrt( xnorm[b,c,w] + snorm[c,k] - 2*sum_s x[b,c,w+s]*h[c,k,s] )
//
// R6 -> R7 changes (post-mortem: global-B reads serialized on MFMA critical path at
// VGPR=60, MfmaUtil 7% -> B must stay in LDS via DMA; R5's real problem was residency:
// 47.6KB LDS -> 3 blocks/CU vs 4 blocks/CU of work -> tail round at 1/3 load):
//  - K split across grid.z (2 halves, 64 shapelets/block): Bs 2x16 -> 2x8 KB,
//    snormC 4 -> 2 KB, dist 64 -> 32 VGPRs. LDS 28.4 KB -> 5 blocks/CU by LDS.
//    Grid 2048 = 8 blocks/CU of work, 4-5 resident -> no 1/3-load tail.
//  - Pipeline identical to R5 (proven 57us): pre-swizzled hbf + linear
//    global_load_lds width=16 DMA, double-buffered Bs/Xr, ONE barrier per c-iter,
//    async x-stage split (load early to regs / f2bf+ds_write late).
//  - No unroll-pinning (R6 lesson: it makes the allocator minimize regs and
//    serialize loads).

typedef short short8 __attribute__((ext_vector_type(8)));
typedef float f32x4 __attribute__((ext_vector_type(4)));

constexpr int Bn = 32, Cn = 8, Ln = 4096, Kn = 128, Sn = 64;
constexpr int Wn = Ln - Sn + 1;          // 4033
constexpr int WT = 128;                  // windows per block
constexpr int NWT = (Wn + WT - 1) / WT;  // 32
constexpr int KH = 64;                   // shapelets per block (k-half)
constexpr int BDIM = 256;

typedef const __attribute__((address_space(1))) unsigned int gas_u32;
typedef __attribute__((address_space(3))) unsigned int las_u32;

__device__ __forceinline__ unsigned int f2bf(float f) {
  unsigned int u = __float_as_uint(f);
  u += 0x7FFFu + ((u >> 16) & 1u);       // round-to-nearest-even
  return u >> 16;
}

// ws layout: [0, 128KB): ushort hbf[C][K][S] = bf16(-2*h), byte-swizzled ^((k&7)<<4)
//            [128KB, +4KB): float snorm[C][K]
__global__ void prep_kernel(const float* __restrict__ sh,
                            unsigned int* __restrict__ out,
                            unsigned short* __restrict__ hbf,
                            float* __restrict__ snorm) {
  int gid = blockIdx.x * blockDim.x + threadIdx.x;  // 0..4095
  out[gid] = 0x7F7FFFFFu;                           // FLT_MAX bits (Bn*Kn == 4096)
  if (gid < Cn * Kn) {
    const float4* row = (const float4*)(sh + (size_t)gid * Sn);
    char* rowb = (char*)hbf + (size_t)gid * (Sn * 2);   // 128B row
    const unsigned int sw = (gid & 7u) << 4;            // (k&7)<<4 byte swizzle
    float a = 0.f;
    #pragma unroll
    for (int i = 0; i < 16; ++i) {
      float4 v = row[i];
      a += v.x * v.x + v.y * v.y + v.z * v.z + v.w * v.w;
      unsigned int p0 = f2bf(-2.f * v.x) | (f2bf(-2.f * v.y) << 16);
      unsigned int p1 = f2bf(-2.f * v.z) | (f2bf(-2.f * v.w) << 16);
      *(uint2*)(rowb + ((8u * i) ^ sw)) = make_uint2(p0, p1);  // stays 8B-aligned
    }
    snorm[gid] = a;
  }
}

__launch_bounds__(BDIM, 2)
__global__ void med_kernel(const float* __restrict__ x,
                           const unsigned short* __restrict__ hbf,
                           const float* __restrict__ snorm,
                           unsigned int* __restrict__ out) {
  constexpr int XRS = 200;  // Xr row stride (elems); 400B, 16B-aligned rows
  __shared__ __align__(16) unsigned short Xr[2][8 * XRS];   // 2 x 3.2KB
  __shared__ __align__(16) unsigned short Bs[2][KH * Sn];   // 2 x 8KB, swizzled
  __shared__ __align__(16) float xnormC[Cn * WT];           // 4KB
  __shared__ __align__(16) float snormC[Cn * KH];           // 2KB

  const int tid  = threadIdx.x;
  const int b    = blockIdx.y;
  const int w0   = blockIdx.x * WT;
  const int kh   = blockIdx.z;   // k-half: shapelets [kh*64, kh*64+64)
  const int lane = tid & 63;
  const int wv   = tid >> 6;     // wave 0..3
  const int quad = lane >> 4;    // 0..3
  const int n16  = lane & 15;
  const int wbase = wv * 32;     // this wave's window offset in tile

  const float* xb = x + (size_t)b * Cn * Ln;

  // ---- B staging: linear global->LDS DMA of pre-swizzled 8KB (c, kh)-slice ----
  auto stage_b = [&](int bufi, int c) {
    const char* src = (const char*)hbf + (size_t)c * (Kn * Sn * 2)
                                       + (size_t)kh * (KH * Sn * 2);
    char* dst = (char*)&Bs[bufi][0];
    #pragma unroll
    for (int rep = 0; rep < 2; ++rep) {
      int q16 = (tid + rep * BDIM) * 16;   // lane-linear 16B chunks, 0..8191
      __builtin_amdgcn_global_load_lds((gas_u32*)(src + q16), (las_u32*)(dst + q16),
                                       16, 0, 0);
    }
  };

  // ---- X staging: c-invariant index math hoisted; load early / write late ----
  int x_lds[3], x_g[3];
  #pragma unroll
  for (int rep = 0; rep < 3; ++rep) {
    int pid = tid + rep * BDIM;       // 0..767
    int r = pid / 96;
    int p = pid - r * 96;             // pair index 0..95 -> elems 2p,2p+1
    x_lds[rep] = r * XRS + 2 * p;
    x_g[rep] = w0 + r + 2 * p;
  }
  float xf[3][2];
  auto load_x = [&](int c) {
    const float* xc = xb + (size_t)c * Ln;
    #pragma unroll
    for (int rep = 0; rep < 3; ++rep) {
      int i0 = x_g[rep];
      xf[rep][0] = (i0 < Ln) ? xc[i0] : 0.f;
      xf[rep][1] = (i0 + 1 < Ln) ? xc[i0 + 1] : 0.f;
    }
  };
  auto write_x = [&](int bufi) {
    #pragma unroll
    for (int rep = 0; rep < 3; ++rep)
      *(unsigned int*)(&Xr[bufi][x_lds[rep]]) =
          f2bf(xf[rep][0]) | (f2bf(xf[rep][1]) << 16);
  };

  // snorm: this k-half's 512 floats (layout snormC[c][64])
  if (tid < 128) {
    int c = tid >> 4, j = tid & 15;
    ((float4*)snormC)[tid] = ((const float4*)snorm)[c * 32 + kh * 16 + j];
  }

  // ---- prologue: stage c=0 into buf 0 (DMA overlaps xnorm compute) ----
  stage_b(0, 0);
  load_x(0);

  // xnorm: 256 threads = 8c x 32 groups, 4 windows each (rolling update), fp32-exact
  {
    int c  = tid >> 5;
    int m0 = (tid & 31) * 4;
    const float* xc = xb + c * Ln;
    auto xq = [&](int i) -> float {
      float v = (i < Ln) ? xc[i] : 0.f;
      return v * v;
    };
    float s0 = 0.f;
    for (int s = 0; s < Sn; ++s) s0 += xq(w0 + m0 + s);
    float s1 = s0 - xq(w0 + m0 + 0) + xq(w0 + m0 + 64);
    float s2 = s1 - xq(w0 + m0 + 1) + xq(w0 + m0 + 65);
    float s3 = s2 - xq(w0 + m0 + 2) + xq(w0 + m0 + 66);
    xnormC[c * WT + m0 + 0] = s0;
    xnormC[c * WT + m0 + 1] = s1;
    xnormC[c * WT + m0 + 2] = s2;
    xnormC[c * WT + m0 + 3] = s3;
  }
  write_x(0);
  __syncthreads();  // drains prologue DMA (implicit vmcnt(0)) + covers norm writes

  float dist[2][4][4] = {};  // [mtile][nt][reg], accumulated over c

  for (int c = 0; c < Cn; ++c) {
    const int buf = c & 1;

    // issue next channel's prefetch BEFORE compute (hides under MFMA+sqrt)
    if (c + 1 < Cn) {
      stage_b(buf ^ 1, c + 1);   // async DMA into other Bs buffer
      load_x(c + 1);             // global loads into regs, waited at write_x
    }

    // xnorm for this wave's 32 windows (C/D row = quad*4+reg) — one b128 each
    float4 xn[2];
    #pragma unroll
    for (int mt = 0; mt < 2; ++mt)
      xn[mt] = *(const float4*)(&xnormC[c * WT + wbase + mt * 16 + quad * 4]);

    // A fragments: lane m = n16, k = quad*8+j (+ks*32); one aligned b128 each
    short8 af[2][2];
    #pragma unroll
    for (int mt = 0; mt < 2; ++mt)
      #pragma unroll
      for (int ks = 0; ks < 2; ++ks) {
        int i = wbase + mt * 16 + n16 + ks * 32 + quad * 8;
        af[mt][ks] = *(const short8*)(&Xr[buf][(i & 7) * XRS + (i >> 3) * 8]);
      }

    // nt-outer / mt-inner: only one (b0,b1) pair (8 VGPRs) live at a time
    const char* bsb = (const char*)&Bs[buf][0];
    #pragma unroll
    for (int nt = 0; nt < 4; ++nt) {
      int ksh = nt * 16 + n16;                       // k-row within half: 0..63
      float sn = snormC[c * KH + ksh];
      int boff = (ksh * 128 + quad * 16) ^ ((ksh & 7) << 4);
      short8 b0 = *(const short8*)(bsb + (boff ^ 0));
      short8 b1 = *(const short8*)(bsb + (boff ^ 64));  // ks=1: +64B, swizzle-safe
      #pragma unroll
      for (int mt = 0; mt < 2; ++mt) {
        f32x4 acc;
        #pragma unroll
        for (int rg = 0; rg < 4; ++rg) acc[rg] = xn[mt][rg] + sn;
        acc = __builtin_amdgcn_mfma_f32_16x16x32_bf16(af[mt][0], b0, acc, 0, 0, 0);
        acc = __builtin_amdgcn_mfma_f32_16x16x32_bf16(af[mt][1], b1, acc, 0, 0, 0);
        // acc == d2 (norms preloaded in C, -2 folded into B)
        #pragma unroll
        for (int rg = 0; rg < 4; ++rg)
          dist[mt][nt][rg] += __builtin_amdgcn_sqrtf(acc[rg]);
      }
    }

    // late half of async-STAGE: convert + write next x tile into other buffer
    if (c + 1 < Cn) write_x(buf ^ 1);
    __syncthreads();  // one barrier per c-iter: publishes Xr writes + drains Bs DMA
  }

  // ---- min over windows, then global combine ----
  const int wql = w0 + wbase + quad * 4;
  #pragma unroll
  for (int nt = 0; nt < 4; ++nt) {
    float v = 3.4e38f;
    #pragma unroll
    for (int mt = 0; mt < 2; ++mt)
      #pragma unroll
      for (int rg = 0; rg < 4; ++rg) {
        int wg = wql + mt * 16 + rg;
        float d = (wg < Wn) ? dist[mt][nt][rg] : 3.4e38f;
        v = fminf(v, d);
      }
    v = fminf(v, __shfl_xor(v, 16, 64));
    v = fminf(v, __shfl_xor(v, 32, 64));
    if (lane < 16)
      atomicMin(&out[b * Kn + kh * KH + nt * 16 + n16], __float_as_uint(v));
  }
}

extern "C" void kernel_launch(void* const* d_in, const int* in_sizes, int n_in,
                              void* d_out, int out_size, void* d_ws, size_t ws_size,
                              hipStream_t stream) {
  const float* x  = (const float*)d_in[0];
  const float* sh = (const float*)d_in[1];
  unsigned int* out = (unsigned int*)d_out;
  unsigned short* hbf = (unsigned short*)d_ws;                      // 128 KB
  float* snorm = (float*)((char*)d_ws + (size_t)Cn * Kn * Sn * 2);  // +4 KB
  hipLaunchKernelGGL(prep_kernel, dim3(16), dim3(256), 0, stream, sh, out, hbf, snorm);
  hipLaunchKernelGGL(med_kernel, dim3(NWT, Bn, 2), dim3(BDIM), 0, stream, x, hbf, snorm, out);
}

// Round 5
// 109.977 us; speedup vs baseline: 1.2850x; 1.1257x over previous
//
#include <hip/hip_runtime.h>

// MinEuclideanDistBlock: x(32,8,4096) f32, shapelets(8,128,64) f32 -> out(32,1,128) f32
// out[b,k] = min_w sum_c sqrt( xnorm[b,c,w] + snorm[c,k] - 2*sum_s x[b,c,w+s]*h[c,k,s] )
//
// R7 -> R8 changes (post-mortem: grid K-split halved compute-per-barrier and duplicated
// the x-side/prologue overhead -> +23%; occupancy remains the only lever but must come
// with per-block work unchanged. R5 = 57.2us reference, 3 blocks/CU, LDS-capped):
//  - Bs re-buffered at PASS granularity: Bs[2][8KB], buffer p holds K-half p.
//    Phase 0: DMA half-1 while computing pass 0; phase 1: DMA next c's half-0 while
//    computing pass 1. Two barriers per c-iter, but each drains a DMA issued a full
//    compute phase (~700 cyc) earlier -> near-free (unlike R3's synchronous staging).
//  - LDS 47.6 -> 30.4 KB: 5 blocks/CU by LDS; VGPR ~112 (R5-proven) -> 4 waves/SIMD
//    -> 4 blocks/CU resident; grid 1024 = exactly one full round, no tail.
//  - Everything else byte-identical to R5: pre-swizzled hbf + linear global_load_lds
//    width=16, Xr double-buffer with async x-stage split, dist[2][8][4] f32, same
//    accumulation order (numerics unchanged).

typedef short short8 __attribute__((ext_vector_type(8)));
typedef float f32x4 __attribute__((ext_vector_type(4)));

constexpr int Bn = 32, Cn = 8, Ln = 4096, Kn = 128, Sn = 64;
constexpr int Wn = Ln - Sn + 1;          // 4033
constexpr int WT = 128;                  // windows per block
constexpr int NWT = (Wn + WT - 1) / WT;  // 32
constexpr int BDIM = 256;

typedef const __attribute__((address_space(1))) unsigned int gas_u32;
typedef __attribute__((address_space(3))) unsigned int las_u32;

__device__ __forceinline__ unsigned int f2bf(float f) {
  unsigned int u = __float_as_uint(f);
  u += 0x7FFFu + ((u >> 16) & 1u);       // round-to-nearest-even
  return u >> 16;
}

// ws layout: [0, 128KB): ushort hbf[C][K][S] = bf16(-2*h), byte-swizzled ^((k&7)<<4)
//            [128KB, +4KB): float snorm[C][K]
__global__ void prep_kernel(const float* __restrict__ sh,
                            unsigned int* __restrict__ out,
                            unsigned short* __restrict__ hbf,
                            float* __restrict__ snorm) {
  int gid = blockIdx.x * blockDim.x + threadIdx.x;  // 0..4095
  out[gid] = 0x7F7FFFFFu;                           // FLT_MAX bits (Bn*Kn == 4096)
  if (gid < Cn * Kn) {
    const float4* row = (const float4*)(sh + (size_t)gid * Sn);
    char* rowb = (char*)hbf + (size_t)gid * (Sn * 2);   // 128B row
    const unsigned int sw = (gid & 7u) << 4;            // (k&7)<<4 byte swizzle
    float a = 0.f;
    #pragma unroll
    for (int i = 0; i < 16; ++i) {
      float4 v = row[i];
      a += v.x * v.x + v.y * v.y + v.z * v.z + v.w * v.w;
      unsigned int p0 = f2bf(-2.f * v.x) | (f2bf(-2.f * v.y) << 16);
      unsigned int p1 = f2bf(-2.f * v.z) | (f2bf(-2.f * v.w) << 16);
      *(uint2*)(rowb + ((8u * i) ^ sw)) = make_uint2(p0, p1);  // stays 8B-aligned
    }
    snorm[gid] = a;
  }
}

__launch_bounds__(BDIM, 2)
__global__ void med_kernel(const float* __restrict__ x,
                           const unsigned short* __restrict__ hbf,
                           const float* __restrict__ snorm,
                           unsigned int* __restrict__ out) {
  constexpr int XRS = 200;  // Xr row stride (elems); 400B, 16B-aligned rows
  __shared__ __align__(16) unsigned short Xr[2][8 * XRS];   // 2 x 3.2KB
  __shared__ __align__(16) unsigned short Bs[2][64 * Sn];   // 2 x 8KB (K-half each)
  __shared__ __align__(16) float xnormC[Cn * WT];           // 4KB
  __shared__ __align__(16) float snormC[Cn * Kn];           // 4KB

  const int tid  = threadIdx.x;
  const int b    = blockIdx.y;
  const int w0   = blockIdx.x * WT;
  const int lane = tid & 63;
  const int wv   = tid >> 6;     // wave 0..3
  const int quad = lane >> 4;    // 0..3
  const int n16  = lane & 15;
  const int wbase = wv * 32;     // this wave's window offset in tile

  const float* xb = x + (size_t)b * Cn * Ln;

  // ---- B staging: linear global->LDS DMA of one pre-swizzled 8KB K-half ----
  auto stage_half = [&](int bufi, int c, int p) {
    const char* src = (const char*)hbf + ((size_t)c * Kn + p * 64) * (Sn * 2);
    char* dst = (char*)&Bs[bufi][0];
    #pragma unroll
    for (int rep = 0; rep < 2; ++rep) {
      int q16 = (tid + rep * BDIM) * 16;   // lane-linear 16B chunks, 0..8191
      __builtin_amdgcn_global_load_lds((gas_u32*)(src + q16), (las_u32*)(dst + q16),
                                       16, 0, 0);
    }
  };

  // ---- X staging: c-invariant index math hoisted; load early / write late ----
  int x_lds[3], x_g[3];
  #pragma unroll
  for (int rep = 0; rep < 3; ++rep) {
    int pid = tid + rep * BDIM;       // 0..767
    int r = pid / 96;
    int p = pid - r * 96;             // pair index 0..95 -> elems 2p,2p+1
    x_lds[rep] = r * XRS + 2 * p;
    x_g[rep] = w0 + r + 2 * p;
  }
  float xf[3][2];
  auto load_x = [&](int c) {
    const float* xc = xb + (size_t)c * Ln;
    #pragma unroll
    for (int rep = 0; rep < 3; ++rep) {
      int i0 = x_g[rep];
      xf[rep][0] = (i0 < Ln) ? xc[i0] : 0.f;
      xf[rep][1] = (i0 + 1 < Ln) ? xc[i0 + 1] : 0.f;
    }
  };
  auto write_x = [&](int bufi) {
    #pragma unroll
    for (int rep = 0; rep < 3; ++rep)
      *(unsigned int*)(&Xr[bufi][x_lds[rep]]) =
          f2bf(xf[rep][0]) | (f2bf(xf[rep][1]) << 16);
  };

  // snorm: one float4 per thread from prep output
  ((float4*)snormC)[tid] = ((const float4*)snorm)[tid];

  // ---- prologue: stage (c=0, pass=0) into Bs[0] (DMA overlaps xnorm compute) ----
  stage_half(0, 0, 0);
  load_x(0);

  // xnorm: 256 threads = 8c x 32 groups, 4 windows each (rolling update), fp32-exact
  {
    int c  = tid >> 5;
    int m0 = (tid & 31) * 4;
    const float* xc = xb + c * Ln;
    auto xq = [&](int i) -> float {
      float v = (i < Ln) ? xc[i] : 0.f;
      return v * v;
    };
    float s0 = 0.f;
    for (int s = 0; s < Sn; ++s) s0 += xq(w0 + m0 + s);
    float s1 = s0 - xq(w0 + m0 + 0) + xq(w0 + m0 + 64);
    float s2 = s1 - xq(w0 + m0 + 1) + xq(w0 + m0 + 65);
    float s3 = s2 - xq(w0 + m0 + 2) + xq(w0 + m0 + 66);
    xnormC[c * WT + m0 + 0] = s0;
    xnormC[c * WT + m0 + 1] = s1;
    xnormC[c * WT + m0 + 2] = s2;
    xnormC[c * WT + m0 + 3] = s3;
  }
  write_x(0);
  __syncthreads();  // drains prologue DMA (implicit vmcnt(0)) + covers norm writes

  float dist[2][8][4] = {};  // [mtile][ntile2][reg] summed distance over c

  for (int c = 0; c < Cn; ++c) {
    const int xbuf = c & 1;

    // ================= phase 0: compute K-half 0, DMA K-half 1 =================
    stage_half(1, c, 1);         // async DMA pass-1 half into Bs[1]
    if (c + 1 < Cn) load_x(c + 1);  // global loads into regs, waited at write_x

    // xnorm for this wave's 32 windows (C/D row = quad*4+reg) — one b128 each
    float4 xn[2];
    #pragma unroll
    for (int mt = 0; mt < 2; ++mt)
      xn[mt] = *(const float4*)(&xnormC[c * WT + wbase + mt * 16 + quad * 4]);

    // A fragments: lane m = n16, k = quad*8+j (+ks*32); one aligned b128 each
    short8 af[2][2];
    #pragma unroll
    for (int mt = 0; mt < 2; ++mt)
      #pragma unroll
      for (int ks = 0; ks < 2; ++ks) {
        int i = wbase + mt * 16 + n16 + ks * 32 + quad * 8;
        af[mt][ks] = *(const short8*)(&Xr[xbuf][(i & 7) * XRS + (i >> 3) * 8]);
      }

    #pragma unroll
    for (int pass = 0; pass < 2; ++pass) {
      // nt-outer / mt-inner: only one (b0,b1) pair (8 VGPRs) live at a time
      const char* bsb = (const char*)&Bs[pass][0];
      #pragma unroll
      for (int nt = 0; nt < 4; ++nt) {
        int ksh = nt * 16 + n16;                    // k-row within this half: 0..63
        float sn = snormC[c * Kn + pass * 64 + ksh];
        int boff = (ksh * 128 + quad * 16) ^ ((ksh & 7) << 4);
        short8 b0 = *(const short8*)(bsb + (boff ^ 0));
        short8 b1 = *(const short8*)(bsb + (boff ^ 64));  // ks=1: +64B, swizzle-safe
        #pragma unroll
        for (int mt = 0; mt < 2; ++mt) {
          f32x4 acc;
          #pragma unroll
          for (int rg = 0; rg < 4; ++rg) acc[rg] = xn[mt][rg] + sn;
          acc = __builtin_amdgcn_mfma_f32_16x16x32_bf16(af[mt][0], b0, acc, 0, 0, 0);
          acc = __builtin_amdgcn_mfma_f32_16x16x32_bf16(af[mt][1], b1, acc, 0, 0, 0);
          // acc == d2 (norms preloaded in C, -2 folded into B)
          #pragma unroll
          for (int rg = 0; rg < 4; ++rg)
            dist[mt][pass * 4 + nt][rg] += __builtin_amdgcn_sqrtf(acc[rg]);
        }
      }

      if (pass == 0) {
        // barrier 1: publishes Bs[1] (DMA issued a full phase ago); Bs[0] now dead
        __syncthreads();
        // ============ phase 1: compute K-half 1, DMA next c's K-half 0 ============
        if (c + 1 < Cn) stage_half(0, c + 1, 0);
      }
    }

    // late half of async-STAGE: convert + write next x tile into other buffer
    if (c + 1 < Cn) write_x(xbuf ^ 1);
    __syncthreads();  // barrier 2: publishes Xr writes + drains next-c DMA
  }

  // ---- min over windows, then global combine ----
  const int wql = w0 + wbase + quad * 4;
  #pragma unroll
  for (int nt2 = 0; nt2 < 8; ++nt2) {
    float v = 3.4e38f;
    #pragma unroll
    for (int mt = 0; mt < 2; ++mt)
      #pragma unroll
      for (int rg = 0; rg < 4; ++rg) {
        int wg = wql + mt * 16 + rg;
        float d = (wg < Wn) ? dist[mt][nt2][rg] : 3.4e38f;
        v = fminf(v, d);
      }
    v = fminf(v, __shfl_xor(v, 16, 64));
    v = fminf(v, __shfl_xor(v, 32, 64));
    if (lane < 16)
      atomicMin(&out[b * Kn + nt2 * 16 + n16], __float_as_uint(v));
  }
}

extern "C" void kernel_launch(void* const* d_in, const int* in_sizes, int n_in,
                              void* d_out, int out_size, void* d_ws, size_t ws_size,
                              hipStream_t stream) {
  const float* x  = (const float*)d_in[0];
  const float* sh = (const float*)d_in[1];
  unsigned int* out = (unsigned int*)d_out;
  unsigned short* hbf = (unsigned short*)d_ws;                      // 128 KB
  float* snorm = (float*)((char*)d_ws + (size_t)Cn * Kn * Sn * 2);  // +4 KB
  hipLaunchKernelGGL(prep_kernel, dim3(16), dim3(256), 0, stream, sh, out, hbf, snorm);
  hipLaunchKernelGGL(med_kernel, dim3(NWT, Bn), dim3(BDIM), 0, stream, x, hbf, snorm, out);
}